// Round 10
// baseline (2045.925 us; speedup 1.0000x reference)
//
#include <hip/hip_runtime.h>
#include <hip/hip_bf16.h>

// Problem constants (reference: B=2,S=2048 -> T=4096; H=1024, I=4096, E=8, 2 steps)
#define T_TOK 4096
#define H_DIM 1024
#define I_DIM 4096
#define E_EXP 8
#define RMS_EPS_F 1e-6f

using bf16x8 = __attribute__((ext_vector_type(8))) __bf16;
using f32x4  = __attribute__((ext_vector_type(4))) float;

__device__ inline void gload_lds16(const void* g, void* l) {
    __builtin_amdgcn_global_load_lds(
        (const __attribute__((address_space(1))) void*)g,
        (__attribute__((address_space(3))) void*)l,
        16, 0, 0);
}

// -------- transpose + fp32->bf16 convert: in [R][C] -> out [C][R], batched over blockIdx.z
__global__ __launch_bounds__(256) void k_transpose_cvt(
    const float* __restrict__ in, __hip_bfloat16* __restrict__ out, int R, int C)
{
    __shared__ float tile[32][33];
    const size_t mat = (size_t)R * C;
    in  += (size_t)blockIdx.z * mat;
    out += (size_t)blockIdx.z * mat;
    const int c0 = blockIdx.x * 32, r0 = blockIdx.y * 32;
    const int tx = threadIdx.x & 31, ty = threadIdx.x >> 5;   // 32 x 8
#pragma unroll
    for (int dy = 0; dy < 32; dy += 8)
        tile[ty + dy][tx] = in[(size_t)(r0 + ty + dy) * C + (c0 + tx)];
    __syncthreads();
#pragma unroll
    for (int dy = 0; dy < 32; dy += 8)
        out[(size_t)(c0 + ty + dy) * R + (r0 + tx)] = __float2bfloat16(tile[tx][ty + dy]);
}

// -------- token prep: x [T,H] fp32 -> tb [T,H] bf16, optional rmsnorm*ln_w. 1 block/token.
__global__ __launch_bounds__(256) void k_prep(
    const float* __restrict__ x, const float* __restrict__ lnw,
    __hip_bfloat16* __restrict__ tb, int do_norm)
{
    const int t = blockIdx.x;
    const float* row = x + (size_t)t * H_DIM;
    const int base = threadIdx.x * 4;
    float4 v = *(const float4*)(row + base);
    if (do_norm) {
        float ss = v.x*v.x + v.y*v.y + v.z*v.z + v.w*v.w;
#pragma unroll
        for (int off = 32; off > 0; off >>= 1) ss += __shfl_xor(ss, off);
        __shared__ float wsum[4];
        const int w = threadIdx.x >> 6;
        if ((threadIdx.x & 63) == 0) wsum[w] = ss;
        __syncthreads();
        const float tot = wsum[0] + wsum[1] + wsum[2] + wsum[3];
        const float scale = rsqrtf(tot * (1.0f / H_DIM) + RMS_EPS_F);
        float4 g = *(const float4*)(lnw + base);
        v.x *= scale * g.x; v.y *= scale * g.y; v.z *= scale * g.z; v.w *= scale * g.w;
    }
    __hip_bfloat16* o = tb + (size_t)t * H_DIM + base;
    o[0] = __float2bfloat16(v.x); o[1] = __float2bfloat16(v.y);
    o[2] = __float2bfloat16(v.z); o[3] = __float2bfloat16(v.w);
}

// -------- gate: logits = tb @ gate_w^T, softmax over E=8. One wave per token.
__global__ __launch_bounds__(256) void k_gate(
    const __hip_bfloat16* __restrict__ tb, const float* __restrict__ gw,
    float* __restrict__ rw)
{
    const int t = blockIdx.x * 4 + (threadIdx.x >> 6);
    const int lane = threadIdx.x & 63;
    const __hip_bfloat16* row = tb + (size_t)t * H_DIM;
    float acc[E_EXP];
#pragma unroll
    for (int e = 0; e < E_EXP; ++e) acc[e] = 0.f;
    for (int h = lane; h < H_DIM; h += 64) {
        const float xv = __bfloat162float(row[h]);
#pragma unroll
        for (int e = 0; e < E_EXP; ++e) acc[e] += xv * gw[e * H_DIM + h];
    }
#pragma unroll
    for (int e = 0; e < E_EXP; ++e) {
#pragma unroll
        for (int off = 32; off > 0; off >>= 1) acc[e] += __shfl_xor(acc[e], off);
    }
    if (lane == 0) {
        float mx = acc[0];
#pragma unroll
        for (int e = 1; e < E_EXP; ++e) mx = fmaxf(mx, acc[e]);
        float ex[E_EXP], s = 0.f;
#pragma unroll
        for (int e = 0; e < E_EXP; ++e) { ex[e] = __expf(acc[e] - mx); s += ex[e]; }
        const float inv = 1.f / s;
#pragma unroll
        for (int e = 0; e < E_EXP; ++e) rw[(size_t)t * E_EXP + e] = ex[e] * inv;
    }
}

// ======== unified 128x64-tile GEMM, 4 waves (2Mx2N of 64x32), BK=64 dbuf, 48KB LDS
//          -> 3 resident blocks/CU (round-9 de-lockstep mechanism, deeper).
// Round-10: (a) XCD-aware flat-id decode — xcd = id&7 owns a contiguous N-slice,
// so the B working set per XCD L2 is <= ~1-2MB and A panels are L3-shared
// (fixes round-9's 540MB over-fetch); (b) MODE 2 is a CONCATENATED-K GEMM:
// K = G*I over hb'[e][T][I] and w2t[e][H][I] (e = kt>>6), with rw pre-folded
// into hb' by MODE 0's epilogue (GEMM2 is linear in hb) and x += acc + sum_e
// rw*b2 fused in the epilogue — eo buffer and k_combine eliminated.
// Register budget: acc[4][2]=32 AGPR + a[4]+b[2]=24 + addr ~30 << 170 (3 w/EU).
// Sync = round-9's proven ledger: stage(t+1 -> buf^1) while reading buf;
// ONE vmcnt(0) + ONE barrier per K-tile. T2 swizzle involution unchanged.

__device__ __forceinline__ void ld_a4(bf16x8 (&a)[4], const char* p, int kof) {
#pragma unroll
    for (int mi = 0; mi < 4; ++mi)
        a[mi] = *(const bf16x8*)(p + mi * 2048 + kof);
}
__device__ __forceinline__ void ld_b2(bf16x8 (&b)[2], const char* p, int kof) {
#pragma unroll
    for (int ni = 0; ni < 2; ++ni)
        b[ni] = *(const bf16x8*)(p + ni * 2048 + kof);
}
__device__ __forceinline__ void mfma8(const bf16x8 (&a)[4], const bf16x8 (&b)[2],
                                      f32x4 (&acc)[4][2]) {
    __builtin_amdgcn_s_setprio(1);
#pragma unroll
    for (int mi = 0; mi < 4; ++mi)
#pragma unroll
        for (int ni = 0; ni < 2; ++ni)
            acc[mi][ni] = __builtin_amdgcn_mfma_f32_16x16x32_bf16(
                a[mi], b[ni], acc[mi][ni], 0, 0, 0);
    __builtin_amdgcn_s_setprio(0);
}

#define BAR()   __builtin_amdgcn_s_barrier()
#define LGKM0() asm volatile("s_waitcnt lgkmcnt(0)" ::: "memory")
#define VMW0()  asm volatile("s_waitcnt vmcnt(0)" ::: "memory")
#define SCHED0() __builtin_amdgcn_sched_barrier(0)

// MODE 0: hb'[z][t][i] = rw[t,e0+z] * silu(tb @ w1t[e0+z]^T + b1[e0+z]); grid 2048*G
// MODE 2: x[t,h] += sum over K=G*I of hb' @ w2t^T  + sum_e rw[t,e]*b2[e,h]; grid 512
template <int MODE, int G>
__global__ __launch_bounds__(256, 3) void k_gemm(
    const __hip_bfloat16* __restrict__ A, int lda,
    const __hip_bfloat16* __restrict__ Bt, int ldb, long long strideBz,
    const float* __restrict__ bias, int biasStride,
    const float* __restrict__ rw, int e0,
    void* __restrict__ out, int ldo, long long strideOutz, int K)
{
    __shared__ __hip_bfloat16 sA[2][128 * 64];   // 32 KB
    __shared__ __hip_bfloat16 sB[2][64 * 64];    // 16 KB

    // ---- XCD-aware decode: xcd = id&7 owns a contiguous N-slice.
    const int id = blockIdx.x;
    const int xcd = id & 7;
    const int local = id >> 3;
    int z, m, n;
    if (MODE == 0) {
        z = local >> 8;                 // 256 blocks per (xcd, z): 32 M x 8 N
        const int r = local & 255;
        n = xcd * 8 + (r & 7);          // N-panels 0..63 (I/64)
        m = r >> 3;                     // 0..31
    } else {
        z = 0;                          // K spans the whole group
        n = xcd * 2 + (local >> 5);     // N-panels 0..15 (H/64)
        m = local & 31;
    }
    const int m0 = m * 128, n0 = n * 64;

    Bt += (size_t)z * (size_t)strideBz;

    const int tid  = threadIdx.x;                // 0..255
    const int lane = tid & 63;
    const int wid  = tid >> 6;                   // 0..3
    const int wr = wid >> 1, wc = wid & 1;       // 2M x 2N waves: 64x32 each

    // ---- staging: dest linear (tid*16); source col pre-swizzled (involution ^(row&7)<<4)
    const int sr  = tid >> 3;                                        // 0..31
    const int skb = ((((tid & 7) * 16) ^ ((sr & 7) << 4)) >> 1);
    const __hip_bfloat16* gA = A  + (size_t)(m0 + sr) * lda + skb;
    const __hip_bfloat16* gB = Bt + (size_t)(n0 + sr) * ldb + skb;
    char* const dA = (char*)&sA[0][0] + tid * 16;
    char* const dB = (char*)&sB[0][0] + tid * 16;

    auto stageA = [&](int bb, int kt) {          // 4 gloads: rows m0+sr+32j
        const __hip_bfloat16* s_;
        if (MODE == 2) {
            const int e = kt >> 6, io = (kt & 63) << 6;
            s_ = gA + (size_t)e * ((size_t)T_TOK * lda) + io;
        } else s_ = gA + (size_t)kt * 64;
#pragma unroll
        for (int j = 0; j < 4; ++j)
            gload_lds16(s_ + (size_t)(32 * j) * lda, dA + bb * 16384 + j * 4096);
    };
    auto stageB = [&](int bb, int kt) {          // 2 gloads: rows n0+sr+32j
        const __hip_bfloat16* s_;
        if (MODE == 2) {
            const int e = kt >> 6, io = (kt & 63) << 6;
            s_ = gB + (size_t)e * ((size_t)H_DIM * ldb) + io;
        } else s_ = gB + (size_t)kt * 64;
#pragma unroll
        for (int j = 0; j < 2; ++j)
            gload_lds16(s_ + (size_t)(32 * j) * ldb, dB + bb * 8192 + j * 4096);
    };

    // ---- ds_read fragment addressing (swizzled)
    const int fr = lane & 15, kg = lane >> 4;
    const int msk  = (fr & 7) << 4;
    const int kof0 = (kg * 16) ^ msk;
    const int kof1 = (64 + kg * 16) ^ msk;
    const char* rdA = (const char*)&sA[0][0] + wr * 8192 + fr * 128;  // wr*64 rows
    const char* rdB = (const char*)&sB[0][0] + wc * 4096 + fr * 128;  // wc*32 rows

    f32x4  acc[4][2] = {};
    bf16x8 a[4], b[2];

    const int NT = K >> 6;

    stageA(0, 0); stageB(0, 0);
    VMW0(); BAR(); SCHED0();

#pragma unroll 2
    for (int t = 0; t < NT; ++t) {
        const int BB = t & 1;
        const char* pA = rdA + BB * 16384;
        const char* pB = rdB + BB * 8192;
        ld_a4(a, pA, kof0); ld_b2(b, pB, kof0);
        if (t < NT - 1) { stageA(BB ^ 1, t + 1); stageB(BB ^ 1, t + 1); }
        LGKM0(); SCHED0();
        mfma8(a, b, acc);
        ld_a4(a, pA, kof1); ld_b2(b, pB, kof1);
        LGKM0(); SCHED0();
        mfma8(a, b, acc);
        VMW0(); BAR(); SCHED0();
    }

    // ---- epilogue. C-frag layout: col = lane&15 (fr), row = kg*4 + j  [m89-verified]
    const int rB = kg * 4;
    const int gn0 = n0 + wc * 32 + fr;           // ni stride 16
    if (MODE == 0) {
        __hip_bfloat16* O = (__hip_bfloat16*)out + (size_t)z * (size_t)strideOutz;
        const float* bz = bias + (size_t)z * biasStride;
        float bv[2];
#pragma unroll
        for (int ni = 0; ni < 2; ++ni) bv[ni] = bz[gn0 + ni * 16];
#pragma unroll
        for (int mi = 0; mi < 4; ++mi) {
#pragma unroll
            for (int j = 0; j < 4; ++j) {
                const int row = m0 + wr * 64 + mi * 16 + rB + j;
                const float rwv = rw[(size_t)row * E_EXP + e0 + z];
#pragma unroll
                for (int ni = 0; ni < 2; ++ni) {
                    float v = acc[mi][ni][j] + bv[ni];
                    v = v / (1.f + __expf(-v));          // silu
                    O[(size_t)row * ldo + gn0 + ni * 16] = __float2bfloat16(rwv * v);
                }
            }
        }
    } else {
        float* O = (float*)out;
        float bc[2][G];
#pragma unroll
        for (int ni = 0; ni < 2; ++ni)
#pragma unroll
            for (int je = 0; je < G; ++je)
                bc[ni][je] = bias[(size_t)je * biasStride + gn0 + ni * 16];
#pragma unroll
        for (int mi = 0; mi < 4; ++mi) {
#pragma unroll
            for (int j = 0; j < 4; ++j) {
                const int row = m0 + wr * 64 + mi * 16 + rB + j;
                float b0 = 0.f, b1v = 0.f;
#pragma unroll
                for (int je = 0; je < G; ++je) {
                    const float rv = rw[(size_t)row * E_EXP + e0 + je];
                    b0  += rv * bc[0][je];
                    b1v += rv * bc[1][je];
                }
                O[(size_t)row * ldo + gn0]      += acc[mi][0][j] + b0;
                O[(size_t)row * ldo + gn0 + 16] += acc[mi][1][j] + b1v;
            }
        }
    }
}

template <int G>
static void launch_group(const __hip_bfloat16* tb, const __hip_bfloat16* w1t,
                         const __hip_bfloat16* w2t, const float* b1, const float* b2,
                         const float* rw, int e0, __hip_bfloat16* hb, float* x,
                         hipStream_t stream)
{
    // GEMM1: hb'[z] = rw .* silu(tb @ w1t[e0+z]^T + b1[e0+z]);  M=T, N=I, K=H
    k_gemm<0, G><<<2048 * G, 256, 0, stream>>>(
        tb, H_DIM,
        w1t + (size_t)e0 * I_DIM * H_DIM, H_DIM, (long long)I_DIM * H_DIM,
        b1 + (size_t)e0 * I_DIM, I_DIM,
        rw, e0,
        hb, I_DIM, (long long)T_TOK * I_DIM, H_DIM);
    // GEMM2K: x += hb' @ w2t^T (K = G*I concatenated) + sum_e rw*b2;  M=T, N=H
    k_gemm<2, G><<<512, 256, 0, stream>>>(
        hb, I_DIM,
        w2t + (size_t)e0 * H_DIM * I_DIM, I_DIM, 0,
        b2 + (size_t)e0 * H_DIM, H_DIM,
        rw, e0,
        x, H_DIM, 0, G * I_DIM);
}

extern "C" void kernel_launch(void* const* d_in, const int* in_sizes, int n_in,
                              void* d_out, int out_size, void* d_ws, size_t ws_size,
                              hipStream_t stream)
{
    const float* hidden = (const float*)d_in[0];
    const float* gate_w = (const float*)d_in[1];
    const float* w1     = (const float*)d_in[2];
    const float* b1     = (const float*)d_in[3];
    const float* w2     = (const float*)d_in[4];
    const float* b2     = (const float*)d_in[5];
    const float* ln_w   = (const float*)d_in[6];
    float* x = (float*)d_out;

    // workspace carve (eo eliminated)
    const size_t w1t_b = (size_t)E_EXP * I_DIM * H_DIM * 2;   // 64 MB
    const size_t w2t_b = (size_t)E_EXP * H_DIM * I_DIM * 2;   // 64 MB
    const size_t tb_b  = (size_t)T_TOK * H_DIM * 2;           //  8 MB
    const size_t rw_b  = (size_t)T_TOK * E_EXP * 4;           // 128 KB
    const size_t hb1_b = (size_t)T_TOK * I_DIM * 2;           // 32 MB per expert
    const size_t base_b = w1t_b + w2t_b + tb_b + rw_b;

    int g = 0;
    for (int cand = 8; cand >= 1; cand >>= 1)
        if (base_b + (size_t)cand * hb1_b <= ws_size) { g = cand; break; }

    char* ws = (char*)d_ws;
    __hip_bfloat16* w1t = (__hip_bfloat16*)ws;  ws += w1t_b;
    __hip_bfloat16* w2t = (__hip_bfloat16*)ws;  ws += w2t_b;
    __hip_bfloat16* tb  = (__hip_bfloat16*)ws;  ws += tb_b;
    float*          rw  = (float*)ws;           ws += rw_b;
    __hip_bfloat16* hb  = (__hip_bfloat16*)ws;

    // x = hidden_states (running residual lives in d_out)
    hipMemcpyAsync(x, hidden, (size_t)T_TOK * H_DIM * 4, hipMemcpyDeviceToDevice, stream);

    if (g == 0) return;  // ws too small (harness has given >= 328 MB so far)

    // bf16 weights in B^T layout: w1t [E][I][H], w2t [E][H][I]
    k_transpose_cvt<<<dim3(I_DIM / 32, H_DIM / 32, E_EXP), 256, 0, stream>>>(w1, w1t, H_DIM, I_DIM);
    k_transpose_cvt<<<dim3(H_DIM / 32, I_DIM / 32, E_EXP), 256, 0, stream>>>(w2, w2t, I_DIM, H_DIM);

    for (int step = 0; step < 2; ++step) {
        k_prep<<<T_TOK, 256, 0, stream>>>(x, ln_w, tb, step);
        k_gate<<<T_TOK / 4, 256, 0, stream>>>(tb, gate_w, rw);

        for (int e0 = 0; e0 < E_EXP; e0 += g) {
            switch (g) {
            case 8: launch_group<8>(tb, w1t, w2t, b1, b2, rw, e0, hb, x, stream); break;
            case 4: launch_group<4>(tb, w1t, w2t, b1, b2, rw, e0, hb, x, stream); break;
            case 2: launch_group<2>(tb, w1t, w2t, b1, b2, rw, e0, hb, x, stream); break;
            default: launch_group<1>(tb, w1t, w2t, b1, b2, rw, e0, hb, x, stream); break;
            }
        }
    }
}

// Round 11
// 1429.989 us; speedup vs baseline: 1.4307x; 1.4307x over previous
//
#include <hip/hip_runtime.h>
#include <hip/hip_bf16.h>

// Problem constants (reference: B=2,S=2048 -> T=4096; H=1024, I=4096, E=8, 2 steps)
#define T_TOK 4096
#define H_DIM 1024
#define I_DIM 4096
#define E_EXP 8
#define RMS_EPS_F 1e-6f

using bf16x8 = __attribute__((ext_vector_type(8))) __bf16;
using f32x4  = __attribute__((ext_vector_type(4))) float;

__device__ inline void gload_lds16(const void* g, void* l) {
    __builtin_amdgcn_global_load_lds(
        (const __attribute__((address_space(1))) void*)g,
        (__attribute__((address_space(3))) void*)l,
        16, 0, 0);
}

// -------- transpose + fp32->bf16 convert: in [R][C] -> out [C][R], batched over blockIdx.z
__global__ __launch_bounds__(256) void k_transpose_cvt(
    const float* __restrict__ in, __hip_bfloat16* __restrict__ out, int R, int C)
{
    __shared__ float tile[32][33];
    const size_t mat = (size_t)R * C;
    in  += (size_t)blockIdx.z * mat;
    out += (size_t)blockIdx.z * mat;
    const int c0 = blockIdx.x * 32, r0 = blockIdx.y * 32;
    const int tx = threadIdx.x & 31, ty = threadIdx.x >> 5;   // 32 x 8
#pragma unroll
    for (int dy = 0; dy < 32; dy += 8)
        tile[ty + dy][tx] = in[(size_t)(r0 + ty + dy) * C + (c0 + tx)];
    __syncthreads();
#pragma unroll
    for (int dy = 0; dy < 32; dy += 8)
        out[(size_t)(c0 + ty + dy) * R + (r0 + tx)] = __float2bfloat16(tile[tx][ty + dy]);
}

// -------- token prep: x [T,H] fp32 -> tb [T,H] bf16, optional rmsnorm*ln_w. 1 block/token.
__global__ __launch_bounds__(256) void k_prep(
    const float* __restrict__ x, const float* __restrict__ lnw,
    __hip_bfloat16* __restrict__ tb, int do_norm)
{
    const int t = blockIdx.x;
    const float* row = x + (size_t)t * H_DIM;
    const int base = threadIdx.x * 4;
    float4 v = *(const float4*)(row + base);
    if (do_norm) {
        float ss = v.x*v.x + v.y*v.y + v.z*v.z + v.w*v.w;
#pragma unroll
        for (int off = 32; off > 0; off >>= 1) ss += __shfl_xor(ss, off);
        __shared__ float wsum[4];
        const int w = threadIdx.x >> 6;
        if ((threadIdx.x & 63) == 0) wsum[w] = ss;
        __syncthreads();
        const float tot = wsum[0] + wsum[1] + wsum[2] + wsum[3];
        const float scale = rsqrtf(tot * (1.0f / H_DIM) + RMS_EPS_F);
        float4 g = *(const float4*)(lnw + base);
        v.x *= scale * g.x; v.y *= scale * g.y; v.z *= scale * g.z; v.w *= scale * g.w;
    }
    __hip_bfloat16* o = tb + (size_t)t * H_DIM + base;
    o[0] = __float2bfloat16(v.x); o[1] = __float2bfloat16(v.y);
    o[2] = __float2bfloat16(v.z); o[3] = __float2bfloat16(v.w);
}

// -------- gate: logits = tb @ gate_w^T, softmax over E=8. One wave per token.
__global__ __launch_bounds__(256) void k_gate(
    const __hip_bfloat16* __restrict__ tb, const float* __restrict__ gw,
    float* __restrict__ rw)
{
    const int t = blockIdx.x * 4 + (threadIdx.x >> 6);
    const int lane = threadIdx.x & 63;
    const __hip_bfloat16* row = tb + (size_t)t * H_DIM;
    float acc[E_EXP];
#pragma unroll
    for (int e = 0; e < E_EXP; ++e) acc[e] = 0.f;
    for (int h = lane; h < H_DIM; h += 64) {
        const float xv = __bfloat162float(row[h]);
#pragma unroll
        for (int e = 0; e < E_EXP; ++e) acc[e] += xv * gw[e * H_DIM + h];
    }
#pragma unroll
    for (int e = 0; e < E_EXP; ++e) {
#pragma unroll
        for (int off = 32; off > 0; off >>= 1) acc[e] += __shfl_xor(acc[e], off);
    }
    if (lane == 0) {
        float mx = acc[0];
#pragma unroll
        for (int e = 1; e < E_EXP; ++e) mx = fmaxf(mx, acc[e]);
        float ex[E_EXP], s = 0.f;
#pragma unroll
        for (int e = 0; e < E_EXP; ++e) { ex[e] = __expf(acc[e] - mx); s += ex[e]; }
        const float inv = 1.f / s;
#pragma unroll
        for (int e = 0; e < E_EXP; ++e) rw[(size_t)t * E_EXP + e] = ex[e] * inv;
    }
}

// ======== 256x256 GEMM, 8 waves (2Mx4N of 128x64), BK=64 dbuf, batched over z.
// Round-11 = round-3's EXACT memory-op ledger (stage slots, VMW(4) placement —
// 3x verified) with the ds_reads SOFTWARE-PIPELINED one phase ahead WITHIN the
// tile (all phases of a tile read the same buffer -> no WAR hazard; lgkmcnt
// is in-order for DS, and each lgkm0 is placed BEFORE issuing the next read
// group so it waits exactly the current group). Barriers: 2/tile (mid-BAR
// separates all b-read issues from STAGE_B, as in R3; boundary BAR after
// VMW(4)). Phase cut = R6's (m-half x kc): operand regs a/b/a2/a2n/bn = 80
// VGPR < R3's 96 -> no spill (R5/R8 lesson). rw is folded into MODE 0's
// epilogue (GEMM2 is linear in hb) and MODE 2 writes eo in bf16.

template<int BB, int MBASE>
__device__ __forceinline__ void ld_a4(bf16x8 (&a)[4], const char* rdA, int kof) {
#pragma unroll
    for (int mi = 0; mi < 4; ++mi)
        a[mi] = *(const bf16x8*)(rdA + BB * 32768 + (MBASE + mi) * 2048 + kof);
}
template<int BB>
__device__ __forceinline__ void ld_b4(bf16x8 (&b)[4], const char* rdB, int kof) {
#pragma unroll
    for (int ni = 0; ni < 4; ++ni)
        b[ni] = *(const bf16x8*)(rdB + BB * 32768 + ni * 2048 + kof);
}
template<int MB>
__device__ __forceinline__ void mfma_cell(const bf16x8 (&a)[4], const bf16x8 (&b)[4],
                                          f32x4 (&acc)[8][4]) {
    __builtin_amdgcn_s_setprio(1);
#pragma unroll
    for (int mi = 0; mi < 4; ++mi)
#pragma unroll
        for (int ni = 0; ni < 4; ++ni)
            acc[MB + mi][ni] = __builtin_amdgcn_mfma_f32_16x16x32_bf16(
                a[mi], b[ni], acc[MB + mi][ni], 0, 0, 0);
    __builtin_amdgcn_s_setprio(0);
}

#define BAR()   __builtin_amdgcn_s_barrier()
#define LGKM0() asm volatile("s_waitcnt lgkmcnt(0)" ::: "memory")
#define VMW(n)  asm volatile("s_waitcnt vmcnt(" #n ")" ::: "memory")
#define SCHED0() __builtin_amdgcn_sched_barrier(0)

// MODE 0: out bf16 = rw[m,e0+z] * silu(acc + bias)   (GEMM1 -> hb', rw folded)
// MODE 2: out bf16 = acc                              (GEMM2 -> eo partials)
template <int MODE>
__global__ __launch_bounds__(512, 2) void k_gemm8(
    const __hip_bfloat16* __restrict__ A, int lda, long long strideA,
    const __hip_bfloat16* __restrict__ Bt, int ldb, long long strideB,
    const float* __restrict__ bias, int strideBias,
    const float* __restrict__ rw, int e0,
    void* __restrict__ out, int ldo, long long strideOut, int K)
{
    __shared__ __hip_bfloat16 sA[2][2][128 * 64];   // 64 KB
    __shared__ __hip_bfloat16 sB[2][2][128 * 64];   // 64 KB

    const int z = blockIdx.z;
    A  += (size_t)z * (size_t)strideA;
    Bt += (size_t)z * (size_t)strideB;

    const int tid  = threadIdx.x;
    const int lane = tid & 63;
    const int wid  = tid >> 6;
    const int wr = wid >> 2, wc = wid & 3;          // 2 x 4 waves
    const int m0 = blockIdx.y * 256, n0 = blockIdx.x * 256;

    // ---- staging: dest linear (tid*16); source col pre-swizzled by involution kbyte ^= (row&7)<<4
    const int sr  = tid >> 3;
    const int skb = ((((tid & 7) * 16) ^ ((sr & 7) << 4)) >> 1);
    const __hip_bfloat16* gA = A  + (size_t)(m0 + sr) * lda + skb;
    const __hip_bfloat16* gB = Bt + (size_t)(n0 + sr) * ldb + skb;
    char* const dA = (char*)&sA[0][0][0] + tid * 16;
    char* const dB = (char*)&sB[0][0][0] + tid * 16;

#define STAGE_A(bb, hh, kt) do { \
    const __hip_bfloat16* s_ = gA + (size_t)(hh) * 128 * lda + (size_t)(kt) * 64; \
    gload_lds16(s_,                     dA + (bb) * 32768 + (hh) * 16384); \
    gload_lds16(s_ + (size_t)64 * lda,  dA + (bb) * 32768 + (hh) * 16384 + 8192); \
} while (0)
#define STAGE_B(bb, hh, kt) do { \
    const __hip_bfloat16* s_ = gB + (size_t)(hh) * 128 * ldb + (size_t)(kt) * 64; \
    gload_lds16(s_,                     dB + (bb) * 32768 + (hh) * 16384); \
    gload_lds16(s_ + (size_t)64 * ldb,  dB + (bb) * 32768 + (hh) * 16384 + 8192); \
} while (0)

    // ---- ds_read fragment addressing (swizzled)
    const int fr = lane & 15, kg = lane >> 4;
    const int msk  = (fr & 7) << 4;
    const int kof0 = (kg * 16) ^ msk;
    const int kof1 = (64 + kg * 16) ^ msk;
    const char* rdA = (const char*)&sA[0][wr][0] + fr * 128;
    const char* rdB = (const char*)&sB[0][wc >> 1][0] + (wc & 1) * 8192 + fr * 128;

    f32x4  acc[8][4] = {};
    bf16x8 a[4], b[4], a2[4], a2n[4], bn[4];

    const int NT = K >> 6;                          // K-tiles of 64 (even, >= 4)

    // ---- prologue: stage T0 (B,A) and T1 (B). 12 gloads; VMW(4) lands T0, leaves B(1)x4.
    STAGE_B(0, 0, 0); STAGE_B(0, 1, 0);
    STAGE_A(0, 0, 0); STAGE_A(0, 1, 0);
    STAGE_B(1, 0, 1); STAGE_B(1, 1, 1);
    VMW(4); BAR(); SCHED0();

    // Pipelined tile (buf BB, tile t): stages A(t+1)->BB^1 @p0/p1, B(t+2)->BB @p2/p3.
    // Reads for phase p+1 are issued under phase p's MFMA (same-buffer -> no WAR).
#define TILE_PIPE(BB, t) do { \
    /* p0: m0-3 x k0 */ \
    ld_a4<BB, 0>(a, rdA, kof0); \
    ld_b4<BB>(b, rdB, kof0); \
    STAGE_A((BB) ^ 1, 0, (t) + 1); \
    LGKM0(); SCHED0(); \
    ld_a4<BB, 4>(a2, rdA, kof0);            /* R(p1) under p0 MFMA */ \
    SCHED0(); \
    mfma_cell<0>(a, b, acc); \
    /* p1: m4-7 x k0 */ \
    STAGE_A((BB) ^ 1, 1, (t) + 1); \
    LGKM0(); SCHED0(); \
    ld_a4<BB, 4>(a2n, rdA, kof1);           /* R(p2) under p1 MFMA */ \
    ld_b4<BB>(bn, rdB, kof1); \
    SCHED0(); \
    mfma_cell<4>(a2, b, acc); \
    BAR();                                   /* all waves issued b(k1) before STAGE_B */ \
    /* p2: m4-7 x k1 */ \
    LGKM0(); SCHED0(); \
    ld_a4<BB, 0>(a, rdA, kof1);             /* R(p3) under p2 MFMA (reuse a) */ \
    SCHED0(); \
    STAGE_B(BB, 0, (t) + 2); \
    mfma_cell<4>(a2n, bn, acc); \
    /* p3: m0-3 x k1 */ \
    LGKM0(); SCHED0(); \
    STAGE_B(BB, 1, (t) + 2); \
    mfma_cell<0>(a, bn, acc); \
    VMW(4); BAR(); SCHED0(); \
} while (0)

    for (int i = 0; i < NT / 2 - 1; ++i) {
        TILE_PIPE(0, 2 * i);
        TILE_PIPE(1, 2 * i + 1);
    }
    {   // ---- tail: tile NT-2 (buf0; stage only A(NT-1); drain), tile NT-1 (buf1; pure reads)
        ld_a4<0, 0>(a, rdA, kof0);
        ld_b4<0>(b, rdB, kof0);
        STAGE_A(1, 0, NT - 1);
        LGKM0(); SCHED0();
        ld_a4<0, 4>(a2, rdA, kof0);
        SCHED0();
        mfma_cell<0>(a, b, acc);
        STAGE_A(1, 1, NT - 1);
        LGKM0(); SCHED0();
        ld_a4<0, 4>(a2n, rdA, kof1);
        ld_b4<0>(bn, rdB, kof1);
        SCHED0();
        mfma_cell<4>(a2, b, acc);
        BAR();
        LGKM0(); SCHED0();
        ld_a4<0, 0>(a, rdA, kof1);
        SCHED0();
        mfma_cell<4>(a2n, bn, acc);
        LGKM0(); SCHED0();
        mfma_cell<0>(a, bn, acc);
        VMW(0); BAR(); SCHED0();
        // tile NT-1 (buf1): nothing writes LDS after the drain
        ld_a4<1, 0>(a, rdA, kof0);
        ld_b4<1>(b, rdB, kof0);
        LGKM0(); SCHED0();
        ld_a4<1, 4>(a2, rdA, kof0);
        SCHED0();
        mfma_cell<0>(a, b, acc);
        LGKM0(); SCHED0();
        ld_a4<1, 4>(a2n, rdA, kof1);
        ld_b4<1>(bn, rdB, kof1);
        SCHED0();
        mfma_cell<4>(a2, b, acc);
        LGKM0(); SCHED0();
        ld_a4<1, 0>(a, rdA, kof1);
        SCHED0();
        mfma_cell<4>(a2n, bn, acc);
        LGKM0(); SCHED0();
        mfma_cell<0>(a, bn, acc);
    }

    // ---- epilogue. C-frag layout: col = lane&15 (fr), row = kg*4 + j  [m89-verified]
    const int rB = kg * 4;
    if (MODE == 0) {
        __hip_bfloat16* O = (__hip_bfloat16*)out + (size_t)z * (size_t)strideOut;
        const float* bz = bias + (size_t)z * (size_t)strideBias;
#pragma unroll
        for (int mi = 0; mi < 8; ++mi) {
            const int gm = m0 + wr * 128 + mi * 16 + rB;
#pragma unroll
            for (int j = 0; j < 4; ++j) {
                const int row = gm + j;
                const float rwv = rw[(size_t)row * E_EXP + e0 + z];
#pragma unroll
                for (int ni = 0; ni < 4; ++ni) {
                    const int gn = n0 + wc * 64 + ni * 16 + fr;
                    float v = acc[mi][ni][j] + bz[gn];
                    v = v / (1.f + __expf(-v));        // silu
                    O[(size_t)row * ldo + gn] = __float2bfloat16(rwv * v);
                }
            }
        }
    } else {
        __hip_bfloat16* O = (__hip_bfloat16*)out + (size_t)z * (size_t)strideOut;
#pragma unroll
        for (int mi = 0; mi < 8; ++mi) {
            const int gm = m0 + wr * 128 + mi * 16 + rB;
#pragma unroll
            for (int ni = 0; ni < 4; ++ni) {
                const int gn = n0 + wc * 64 + ni * 16 + fr;
#pragma unroll
                for (int j = 0; j < 4; ++j)
                    O[(size_t)(gm + j) * ldo + gn] = __float2bfloat16(acc[mi][ni][j]);
            }
        }
    }
#undef STAGE_A
#undef STAGE_B
#undef TILE_PIPE
}

// -------- combine: x[t,h] += sum_j eo[j][t][h] + sum_j rw[t,e0+j]*b2[e0+j][h].
// (rw already folded into eo via GEMM1's epilogue). eo is bf16. 1 block/token.
__global__ __launch_bounds__(256) void k_combine(
    const __hip_bfloat16* __restrict__ eo, const float* __restrict__ rw,
    const float* __restrict__ b2, float* __restrict__ x, int e0, int g)
{
    const int t = blockIdx.x;
    const int h = threadIdx.x * 4;
    float4 acc = *(const float4*)(x + (size_t)t * H_DIM + h);
    for (int j = 0; j < g; ++j) {
        const float w = rw[(size_t)t * E_EXP + e0 + j];
        const __hip_bfloat16* p = eo + ((size_t)j * T_TOK + t) * H_DIM + h;
        const float4 bz = *(const float4*)(b2 + (size_t)(e0 + j) * H_DIM + h);
        acc.x += __bfloat162float(p[0]) + w * bz.x;
        acc.y += __bfloat162float(p[1]) + w * bz.y;
        acc.z += __bfloat162float(p[2]) + w * bz.z;
        acc.w += __bfloat162float(p[3]) + w * bz.w;
    }
    *(float4*)(x + (size_t)t * H_DIM + h) = acc;
}

extern "C" void kernel_launch(void* const* d_in, const int* in_sizes, int n_in,
                              void* d_out, int out_size, void* d_ws, size_t ws_size,
                              hipStream_t stream)
{
    const float* hidden = (const float*)d_in[0];
    const float* gate_w = (const float*)d_in[1];
    const float* w1     = (const float*)d_in[2];
    const float* b1     = (const float*)d_in[3];
    const float* w2     = (const float*)d_in[4];
    const float* b2     = (const float*)d_in[5];
    const float* ln_w   = (const float*)d_in[6];
    float* x = (float*)d_out;

    // workspace carve
    const size_t w1t_b = (size_t)E_EXP * I_DIM * H_DIM * 2;   // 64 MB
    const size_t w2t_b = (size_t)E_EXP * H_DIM * I_DIM * 2;   // 64 MB
    const size_t tb_b  = (size_t)T_TOK * H_DIM * 2;           //  8 MB
    const size_t rw_b  = (size_t)T_TOK * E_EXP * 4;           // 128 KB
    const size_t hb1_b = (size_t)T_TOK * I_DIM * 2;           // 32 MB per expert
    const size_t eo1_b = (size_t)T_TOK * H_DIM * 2;           //  8 MB per expert (bf16)
    const size_t base_b = w1t_b + w2t_b + tb_b + rw_b;

    // largest expert group that fits
    int g = 0;
    for (int cand = 8; cand >= 1; cand >>= 1)
        if (base_b + (size_t)cand * (hb1_b + eo1_b) <= ws_size) { g = cand; break; }

    char* ws = (char*)d_ws;
    __hip_bfloat16* w1t = (__hip_bfloat16*)ws;  ws += w1t_b;
    __hip_bfloat16* w2t = (__hip_bfloat16*)ws;  ws += w2t_b;
    __hip_bfloat16* tb  = (__hip_bfloat16*)ws;  ws += tb_b;
    float*          rw  = (float*)ws;           ws += rw_b;
    __hip_bfloat16* hb  = (__hip_bfloat16*)ws;
    __hip_bfloat16* eo  = (__hip_bfloat16*)(ws + (size_t)(g > 0 ? g : 1) * hb1_b);

    // x = hidden_states (running residual lives in d_out)
    hipMemcpyAsync(x, hidden, (size_t)T_TOK * H_DIM * 4, hipMemcpyDeviceToDevice, stream);

    if (g == 0) return;  // ws too small (harness has given >= 328 MB so far)

    // bf16 weights in B^T layout: w1t [E][I][H], w2t [E][H][I]
    k_transpose_cvt<<<dim3(I_DIM / 32, H_DIM / 32, E_EXP), 256, 0, stream>>>(w1, w1t, H_DIM, I_DIM);
    k_transpose_cvt<<<dim3(H_DIM / 32, I_DIM / 32, E_EXP), 256, 0, stream>>>(w2, w2t, I_DIM, H_DIM);

    for (int step = 0; step < 2; ++step) {
        k_prep<<<T_TOK, 256, 0, stream>>>(x, ln_w, tb, step);
        k_gate<<<T_TOK / 4, 256, 0, stream>>>(tb, gate_w, rw);

        for (int e0 = 0; e0 < E_EXP; e0 += g) {
            // GEMM1: hb'[z] = rw .* silu(tb @ w1t[e0+z]^T + b1[e0+z]);  M=T, N=I, K=H
            k_gemm8<0><<<dim3(I_DIM / 256, T_TOK / 256, g), 512, 0, stream>>>(
                tb, H_DIM, 0,
                w1t + (size_t)e0 * I_DIM * H_DIM, H_DIM, (long long)I_DIM * H_DIM,
                b1 + (size_t)e0 * I_DIM, I_DIM,
                rw, e0,
                hb, I_DIM, (long long)T_TOK * I_DIM, H_DIM);
            // GEMM2: eo[z] = hb'[z] @ w2t[e0+z]^T  (bf16 partials), M=T, N=H, K=I
            k_gemm8<2><<<dim3(H_DIM / 256, T_TOK / 256, g), 512, 0, stream>>>(
                hb, I_DIM, (long long)T_TOK * I_DIM,
                w2t + (size_t)e0 * H_DIM * I_DIM, I_DIM, (long long)H_DIM * I_DIM,
                nullptr, 0,
                nullptr, 0,
                eo, H_DIM, (long long)T_TOK * H_DIM, I_DIM);
            // x += sum_j eo_j + sum_j rw_j*b2_j
            k_combine<<<T_TOK, 256, 0, stream>>>(eo, rw, b2, x, e0, g);
        }
    }
}